// Round 1
// baseline (562.503 us; speedup 1.0000x reference)
//
#include <hip/hip_runtime.h>
#include <hip/hip_bf16.h>

#define SEQ 8192
#define DIM 1024
#define NN  4096
#define KE  3072   // 3*DIM: [x_hi | x_lo | x_hi] vs [W_hi | W_hi | W_lo]

using frag_t = __attribute__((ext_vector_type(8))) short;  // 8 bf16 = 4 VGPRs
using f32x4  = __attribute__((ext_vector_type(4))) float;  // 4 fp32 acc

__device__ __forceinline__ void gld_lds16(const void* g, void* l) {
    __builtin_amdgcn_global_load_lds(
        (const __attribute__((address_space(1))) unsigned int*)g,
        (__attribute__((address_space(3))) unsigned int*)l,
        16, 0, 0);
}

__device__ __forceinline__ unsigned short h2u(__hip_bfloat16 h) {
    unsigned short u; __builtin_memcpy(&u, &h, 2); return u;
}

// ---------------------------------------------------------------------------
// Convert x [SEQ][DIM] fp32 -> A' [SEQ][KE] bf16 = [hi | lo | hi]
__global__ __launch_bounds__(256) void convert_x_kernel(
        const float* __restrict__ x, unsigned short* __restrict__ A) {
    int t   = blockIdx.x * 256 + threadIdx.x;
    int idx = t * 4;                       // element index into x
    int m = idx >> 10;                     // /DIM (1024)
    int k = idx & 1023;
    float4 v = *(const float4*)(x + idx);
    float f[4] = {v.x, v.y, v.z, v.w};
    unsigned short hi[4], lo[4];
#pragma unroll
    for (int i = 0; i < 4; i++) {
        __hip_bfloat16 h = __float2bfloat16(f[i]);
        float hf = __bfloat162float(h);
        __hip_bfloat16 l = __float2bfloat16(f[i] - hf);
        hi[i] = h2u(h); lo[i] = h2u(l);
    }
    ushort4 hv = make_ushort4(hi[0], hi[1], hi[2], hi[3]);
    ushort4 lv = make_ushort4(lo[0], lo[1], lo[2], lo[3]);
    size_t base = (size_t)m * KE + k;
    *(ushort4*)(A + base)        = hv;   // chunk 0: x_hi
    *(ushort4*)(A + base + 1024) = lv;   // chunk 1: x_lo
    *(ushort4*)(A + base + 2048) = hv;   // chunk 2: x_hi
}

// Convert W [NN][DIM] fp32 -> B' [NN][KE] bf16 = [hi | hi | lo]
__global__ __launch_bounds__(256) void convert_w_kernel(
        const float* __restrict__ w, unsigned short* __restrict__ B) {
    int t   = blockIdx.x * 256 + threadIdx.x;
    int idx = t * 4;
    int n = idx >> 10;
    int k = idx & 1023;
    float4 v = *(const float4*)(w + idx);
    float f[4] = {v.x, v.y, v.z, v.w};
    unsigned short hi[4], lo[4];
#pragma unroll
    for (int i = 0; i < 4; i++) {
        __hip_bfloat16 h = __float2bfloat16(f[i]);
        float hf = __bfloat162float(h);
        __hip_bfloat16 l = __float2bfloat16(f[i] - hf);
        hi[i] = h2u(h); lo[i] = h2u(l);
    }
    ushort4 hv = make_ushort4(hi[0], hi[1], hi[2], hi[3]);
    ushort4 lv = make_ushort4(lo[0], lo[1], lo[2], lo[3]);
    size_t base = (size_t)n * KE + k;
    *(ushort4*)(B + base)        = hv;   // chunk 0: W_hi
    *(ushort4*)(B + base + 1024) = hv;   // chunk 1: W_hi
    *(ushort4*)(B + base + 2048) = lv;   // chunk 2: W_lo
}

// ---------------------------------------------------------------------------
// GEMM: out[m][n] = tanh( sum_k A'[m][k]*B'[n][k] + bias[n] )
// 128x128 tile, BK=32, 4 waves in 2x2, each wave 64x64 via 4x4 MFMA 16x16x32.
// LDS in "fragment order": tile t (16 rows x 32 k) stored as 64 lanes x 16B,
// lane l = (k_quad<<4) | row15  -> matches both global_load_lds deposit
// (uniform base + lane*16) and conflict-free linear ds_read_b128 of frags.
__global__ __launch_bounds__(256) void gemm_tanh_kernel(
        const short* __restrict__ A,     // [SEQ][KE] bf16 bits
        const short* __restrict__ B,     // [NN][KE]  bf16 bits
        const float* __restrict__ bias,  // [NN]
        float* __restrict__ out) {       // [SEQ][NN]
    __shared__ __align__(16) short As[8 * 512];   // 8 KB
    __shared__ __align__(16) short Bs[8 * 512];   // 8 KB

    const int tid  = threadIdx.x;
    const int lane = tid & 63;
    const int wave = tid >> 6;       // 0..3
    const int wm   = wave >> 1;      // 0..1 (row half)
    const int wn   = wave & 1;       // 0..1 (col half)

    const int n_blk = blockIdx.x * 128;
    const int m_blk = blockIdx.y * 128;

    // Staging: wave stages A tiles {2w, 2w+1} and B tiles {2w, 2w+1}
    const int r15  = lane & 15;
    const int quad = lane >> 4;
    const short* ag0 = A + (size_t)(m_blk + wave * 32 + r15) * KE + quad * 8;
    const short* ag1 = ag0 + (size_t)16 * KE;
    const short* bg0 = B + (size_t)(n_blk + wave * 32 + r15) * KE + quad * 8;
    const short* bg1 = bg0 + (size_t)16 * KE;
    short* as0 = As + (wave * 2) * 512;   // wave-uniform LDS bases
    short* as1 = as0 + 512;
    short* bs0 = Bs + (wave * 2) * 512;
    short* bs1 = bs0 + 512;

    f32x4 acc[4][4] = {};

    for (int k0 = 0; k0 < KE; k0 += 32) {
        __syncthreads();   // prior iter's fragment reads done before restage
        gld_lds16(ag0 + k0, as0);
        gld_lds16(ag1 + k0, as1);
        gld_lds16(bg0 + k0, bs0);
        gld_lds16(bg1 + k0, bs1);
        __syncthreads();   // drains vmcnt -> staging visible

        frag_t a[4], b[4];
#pragma unroll
        for (int i = 0; i < 4; i++)
            a[i] = *(const frag_t*)(As + (wm * 4 + i) * 512 + lane * 8);
#pragma unroll
        for (int j = 0; j < 4; j++)
            b[j] = *(const frag_t*)(Bs + (wn * 4 + j) * 512 + lane * 8);
#pragma unroll
        for (int i = 0; i < 4; i++)
#pragma unroll
            for (int j = 0; j < 4; j++)
                acc[i][j] = __builtin_amdgcn_mfma_f32_16x16x32_bf16(
                    a[i], b[j], acc[i][j], 0, 0, 0);
    }

    // Epilogue: C/D layout col = lane&15, row = quad*4 + reg
    const int col0 = n_blk + wn * 64 + r15;
    const int row0 = m_blk + wm * 64 + quad * 4;
#pragma unroll
    for (int j = 0; j < 4; j++) {
        const int col = col0 + j * 16;
        const float bj = bias[col];
#pragma unroll
        for (int i = 0; i < 4; i++) {
            const int row = row0 + i * 16;
#pragma unroll
            for (int r = 0; r < 4; r++)
                out[(size_t)(row + r) * NN + col] = tanhf(acc[i][j][r] + bj);
        }
    }
}

// ---------------------------------------------------------------------------
// Fallback (only if workspace too small): naive fp32 tiled GEMM.
__global__ void naive_gemm_kernel(const float* __restrict__ x,
                                  const float* __restrict__ W,
                                  const float* __restrict__ b,
                                  float* __restrict__ out) {
    __shared__ float xs[16][17], ws[16][17];
    int n = blockIdx.x * 16 + threadIdx.x;
    int m = blockIdx.y * 16 + threadIdx.y;
    float s = 0.f;
    for (int k0 = 0; k0 < DIM; k0 += 16) {
        xs[threadIdx.y][threadIdx.x] = x[(size_t)m * DIM + k0 + threadIdx.x];
        ws[threadIdx.y][threadIdx.x] =
            W[(size_t)(blockIdx.x * 16 + threadIdx.y) * DIM + k0 + threadIdx.x];
        __syncthreads();
#pragma unroll
        for (int kk = 0; kk < 16; kk++) s += xs[threadIdx.y][kk] * ws[threadIdx.x][kk];
        __syncthreads();
    }
    out[(size_t)m * NN + n] = tanhf(s + b[n]);
}

// ---------------------------------------------------------------------------
extern "C" void kernel_launch(void* const* d_in, const int* in_sizes, int n_in,
                              void* d_out, int out_size, void* d_ws, size_t ws_size,
                              hipStream_t stream) {
    const float* x = (const float*)d_in[0];
    const float* W = (const float*)d_in[1];
    const float* b = (const float*)d_in[2];
    float* out = (float*)d_out;

    const size_t need = ((size_t)SEQ + (size_t)NN) * KE * sizeof(short);
    if (ws_size < need) {
        dim3 grid(NN / 16, SEQ / 16), block(16, 16);
        naive_gemm_kernel<<<grid, block, 0, stream>>>(x, W, b, out);
        return;
    }

    unsigned short* Abuf = (unsigned short*)d_ws;
    unsigned short* Bbuf = Abuf + (size_t)SEQ * KE;

    convert_x_kernel<<<(SEQ * DIM / 4) / 256, 256, 0, stream>>>(x, Abuf);
    convert_w_kernel<<<(NN * DIM / 4) / 256, 256, 0, stream>>>(W, Bbuf);

    dim3 grid(NN / 128, SEQ / 128);  // (32, 64)
    gemm_tanh_kernel<<<grid, 256, 0, stream>>>(
        (const short*)Abuf, (const short*)Bbuf, b, out);
}

// Round 2
// 507.795 us; speedup vs baseline: 1.1077x; 1.1077x over previous
//
#include <hip/hip_runtime.h>
#include <hip/hip_bf16.h>

#define SEQ 8192
#define DIM 1024
#define NN  4096
#define KE  3072            // 3*DIM: [x_hi | x_lo | x_hi] . [W_hi | W_hi | W_lo]
#define NT  96              // KE/32 k-tiles
#define NT3 32              // tiles per chunk

using frag_t  = __attribute__((ext_vector_type(8))) short;           // 8 bf16
using us8     = __attribute__((ext_vector_type(8))) unsigned short;
using f32x4   = __attribute__((ext_vector_type(4))) float;

__device__ __forceinline__ unsigned short h2u(__hip_bfloat16 h) {
    unsigned short u; __builtin_memcpy(&u, &h, 2); return u;
}

__device__ __forceinline__ float fast_tanh(float x) {
    float e = __expf(2.0f * x);            // v_exp_f32 path
    return 1.0f - 2.0f / (e + 1.0f);
}

// ---------------------------------------------------------------------------
// A'' layout: [p=0..127][t=0..95][i=0..3][lane=0..63][8 bf16]
//   element: x_row = p*64 + i*16 + (lane&15), k = (t%32)*32 + (lane>>4)*8 ..+8
//   tiles 0..31 = x_hi, 32..63 = x_lo, 64..95 = x_hi
__global__ __launch_bounds__(256) void convert_x_kernel(
        const float* __restrict__ x, unsigned short* __restrict__ A) {
    const int lane = threadIdx.x & 63;
    const int i    = threadIdx.x >> 6;       // 0..3
    const int p    = blockIdx.x >> 5;        // 0..127
    const int t    = blockIdx.x & 31;        // 0..31
    const int row  = p * 64 + i * 16 + (lane & 15);
    const int k    = t * 32 + (lane >> 4) * 8;
    const float* src = x + (size_t)row * DIM + k;
    float4 v0 = *(const float4*)src;
    float4 v1 = *(const float4*)(src + 4);
    float f[8] = {v0.x, v0.y, v0.z, v0.w, v1.x, v1.y, v1.z, v1.w};
    us8 hv, lv;
#pragma unroll
    for (int e = 0; e < 8; e++) {
        __hip_bfloat16 h = __float2bfloat16(f[e]);
        __hip_bfloat16 l = __float2bfloat16(f[e] - __bfloat162float(h));
        hv[e] = h2u(h); lv[e] = h2u(l);
    }
    size_t frag = (((size_t)p * NT + t) * 4 + i) * 64 + lane;  // frag index
    us8* dst = (us8*)A;
    dst[frag]                 = hv;   // chunk 0: x_hi
    dst[frag + 32ull * 256]   = lv;   // chunk 1: x_lo   (32 tiles * 256 frags)
    dst[frag + 64ull * 256]   = hv;   // chunk 2: x_hi
}

// B'' layout: [q=0..63][t=0..95][j=0..3][lane][8]
//   W_row(n) = q*64 + j*16 + (lane&15); tiles 0..31 = W_hi, 32..63 = W_hi, 64..95 = W_lo
__global__ __launch_bounds__(256) void convert_w_kernel(
        const float* __restrict__ w, unsigned short* __restrict__ B) {
    const int lane = threadIdx.x & 63;
    const int j    = threadIdx.x >> 6;
    const int q    = blockIdx.x >> 5;        // 0..63
    const int t    = blockIdx.x & 31;
    const int row  = q * 64 + j * 16 + (lane & 15);
    const int k    = t * 32 + (lane >> 4) * 8;
    const float* src = w + (size_t)row * DIM + k;
    float4 v0 = *(const float4*)src;
    float4 v1 = *(const float4*)(src + 4);
    float f[8] = {v0.x, v0.y, v0.z, v0.w, v1.x, v1.y, v1.z, v1.w};
    us8 hv, lv;
#pragma unroll
    for (int e = 0; e < 8; e++) {
        __hip_bfloat16 h = __float2bfloat16(f[e]);
        __hip_bfloat16 l = __float2bfloat16(f[e] - __bfloat162float(h));
        hv[e] = h2u(h); lv[e] = h2u(l);
    }
    size_t frag = (((size_t)q * NT + t) * 4 + j) * 64 + lane;
    us8* dst = (us8*)B;
    dst[frag]                 = hv;   // chunk 0: W_hi
    dst[frag + 32ull * 256]   = hv;   // chunk 1: W_hi
    dst[frag + 64ull * 256]   = lv;   // chunk 2: W_lo
}

// ---------------------------------------------------------------------------
// Barrier-free GEMM. One wave owns a 64x64 output tile: 4x4 of 16x16x32 MFMA.
// Fragments loaded directly global->VGPR from the pre-swizzled layout,
// register double-buffered (prefetch t+1 during MFMA on t). No LDS, no
// __syncthreads -> compiler emits partial vmcnt waits, loads stay in flight.
__global__ __launch_bounds__(256, 3) void gemm_tanh_kernel(
        const frag_t* __restrict__ A,    // [128][96][4][64] frags
        const frag_t* __restrict__ B,    // [64][96][4][64] frags
        const float* __restrict__ bias,  // [NN]
        float* __restrict__ out) {       // [SEQ][NN]
    const int tid  = threadIdx.x;
    const int lane = tid & 63;
    const int wave = tid >> 6;

    // XCD swizzle: give each XCD a contiguous q-range (B-panel L2 locality)
    const int blk = (blockIdx.x & 7) * 256 + (blockIdx.x >> 3);
    const int w   = blk * 4 + wave;          // 0..8191
    const int q   = w >> 7;                  // n-panel 0..63
    const int p   = w & 127;                 // m-panel 0..127

    const frag_t* Ab = A + ((size_t)p * NT) * 256 + lane;  // +t*256 +i*64
    const frag_t* Bb = B + ((size_t)q * NT) * 256 + lane;

    f32x4 acc[4][4] = {};
    frag_t a0[4], b0[4], a1[4], b1[4];

#pragma unroll
    for (int i = 0; i < 4; i++) { a0[i] = Ab[i * 64]; b0[i] = Bb[i * 64]; }

    for (int t = 0; t < NT; t += 2) {
        const frag_t* An = Ab + (t + 1) * 256;
        const frag_t* Bn = Bb + (t + 1) * 256;
#pragma unroll
        for (int i = 0; i < 4; i++) { a1[i] = An[i * 64]; b1[i] = Bn[i * 64]; }
#pragma unroll
        for (int i = 0; i < 4; i++)
#pragma unroll
            for (int j = 0; j < 4; j++)
                acc[i][j] = __builtin_amdgcn_mfma_f32_16x16x32_bf16(
                    a0[i], b0[j], acc[i][j], 0, 0, 0);

        const int t2 = (t + 2 < NT) ? (t + 2) : 0;   // last prefetch harmless
        const frag_t* An2 = Ab + t2 * 256;
        const frag_t* Bn2 = Bb + t2 * 256;
#pragma unroll
        for (int i = 0; i < 4; i++) { a0[i] = An2[i * 64]; b0[i] = Bn2[i * 64]; }
#pragma unroll
        for (int i = 0; i < 4; i++)
#pragma unroll
            for (int j = 0; j < 4; j++)
                acc[i][j] = __builtin_amdgcn_mfma_f32_16x16x32_bf16(
                    a1[i], b1[j], acc[i][j], 0, 0, 0);
    }

    // Epilogue: C/D layout col = lane&15 (n), row = (lane>>4)*4 + reg (m)
    const int r15  = lane & 15;
    const int quad = lane >> 4;
    const int col0 = q * 64 + r15;
    const int row0 = p * 64 + quad * 4;
#pragma unroll
    for (int j = 0; j < 4; j++) {
        const int col = col0 + j * 16;
        const float bj = bias[col];
#pragma unroll
        for (int i = 0; i < 4; i++) {
            const int row = row0 + i * 16;
#pragma unroll
            for (int r = 0; r < 4; r++)
                out[(size_t)(row + r) * NN + col] = fast_tanh(acc[i][j][r] + bj);
        }
    }
}

// ---------------------------------------------------------------------------
// Fallback (only if workspace too small): naive fp32 tiled GEMM.
__global__ void naive_gemm_kernel(const float* __restrict__ x,
                                  const float* __restrict__ W,
                                  const float* __restrict__ b,
                                  float* __restrict__ out) {
    __shared__ float xs[16][17], ws[16][17];
    int n = blockIdx.x * 16 + threadIdx.x;
    int m = blockIdx.y * 16 + threadIdx.y;
    float s = 0.f;
    for (int k0 = 0; k0 < DIM; k0 += 16) {
        xs[threadIdx.y][threadIdx.x] = x[(size_t)m * DIM + k0 + threadIdx.x];
        ws[threadIdx.y][threadIdx.x] =
            W[(size_t)(blockIdx.x * 16 + threadIdx.y) * DIM + k0 + threadIdx.x];
        __syncthreads();
#pragma unroll
        for (int kk = 0; kk < 16; kk++) s += xs[threadIdx.y][kk] * ws[threadIdx.x][kk];
        __syncthreads();
    }
    out[(size_t)m * NN + n] = tanhf(s + b[n]);
}

// ---------------------------------------------------------------------------
extern "C" void kernel_launch(void* const* d_in, const int* in_sizes, int n_in,
                              void* d_out, int out_size, void* d_ws, size_t ws_size,
                              hipStream_t stream) {
    const float* x = (const float*)d_in[0];
    const float* W = (const float*)d_in[1];
    const float* b = (const float*)d_in[2];
    float* out = (float*)d_out;

    const size_t need = ((size_t)SEQ + (size_t)NN) * KE * sizeof(short);
    if (ws_size < need) {
        dim3 grid(NN / 16, SEQ / 16), block(16, 16);
        naive_gemm_kernel<<<grid, block, 0, stream>>>(x, W, b, out);
        return;
    }

    unsigned short* Abuf = (unsigned short*)d_ws;
    unsigned short* Bbuf = Abuf + (size_t)SEQ * KE;

    convert_x_kernel<<<128 * 32, 256, 0, stream>>>(x, Abuf);   // 4096 blocks
    convert_w_kernel<<<64 * 32, 256, 0, stream>>>(W, Bbuf);    // 2048 blocks

    gemm_tanh_kernel<<<2048, 256, 0, stream>>>(
        (const frag_t*)Abuf, (const frag_t*)Bbuf, b, out);
}

// Round 3
// 408.497 us; speedup vs baseline: 1.3770x; 1.2431x over previous
//
#include <hip/hip_runtime.h>
#include <hip/hip_bf16.h>

#define SEQ 8192
#define DIM 1024
#define NN  4096
#define KE  3072            // 3*DIM: [x_hi | x_lo | x_hi] . [W_hi | W_hi | W_lo]
#define NT  96              // KE/32 k-tiles
#define CHUNK_FRAGS (32 * 256)   // 32 tiles * 256 frags per chunk

using frag_t  = __attribute__((ext_vector_type(8))) short;           // 8 bf16
using us8     = __attribute__((ext_vector_type(8))) unsigned short;
using f32x4   = __attribute__((ext_vector_type(4))) float;

__device__ __forceinline__ unsigned short h2u(__hip_bfloat16 h) {
    unsigned short u; __builtin_memcpy(&u, &h, 2); return u;
}

__device__ __forceinline__ float fast_tanh(float x) {
    float e = __expf(2.0f * x);
    return 1.0f - 2.0f / (e + 1.0f);
}

// ---------------------------------------------------------------------------
// Layout (both operands): frag_idx = (panel*NT + t)*256 + i*64 + quad*16 + l15
//   holds elem[row = panel*64 + i*16 + l15][k = t*32 + quad*8 + e], e=0..7
// Convert mapping: block = (panel, t0); unit u = tid + 256*c (c=0..3):
//   row_local = u>>4 (i = c, l15 = tid>>4), k8_local = u&15 (t_l = k8>>2,
//   quad = k8&3). Reads: 512B contiguous runs. Writes: 16 full 64B lines/wave.
__global__ __launch_bounds__(256) void convert_x_kernel(
        const float* __restrict__ x, us8* __restrict__ A) {
    const int tid = threadIdx.x;
    const int p   = blockIdx.x >> 3;         // 0..127
    const int t0  = blockIdx.x & 7;          // 0..7
    const int k8l = tid & 15;                // k8 within block
    const int rl0 = tid >> 4;                // row_local base (0..15)
#pragma unroll
    for (int c = 0; c < 4; c++) {
        const int row_local = rl0 + 16 * c;
        const float* src = x + (size_t)(p * 64 + row_local) * DIM + t0 * 128 + k8l * 8;
        float4 v0 = *(const float4*)src;
        float4 v1 = *(const float4*)(src + 4);
        float f[8] = {v0.x, v0.y, v0.z, v0.w, v1.x, v1.y, v1.z, v1.w};
        us8 hv, lv;
#pragma unroll
        for (int e = 0; e < 8; e++) {
            __hip_bfloat16 h = __float2bfloat16(f[e]);
            __hip_bfloat16 l = __float2bfloat16(f[e] - __bfloat162float(h));
            hv[e] = h2u(h); lv[e] = h2u(l);
        }
        const int t    = t0 * 4 + (k8l >> 2);
        const int quad = k8l & 3;
        const size_t frag = ((size_t)p * NT + t) * 256 + c * 64 + quad * 16 + rl0;
        A[frag]                   = hv;   // chunk 0: x_hi
        A[frag + CHUNK_FRAGS]     = lv;   // chunk 1: x_lo
        A[frag + 2 * CHUNK_FRAGS] = hv;   // chunk 2: x_hi
    }
}

__global__ __launch_bounds__(256) void convert_w_kernel(
        const float* __restrict__ w, us8* __restrict__ B) {
    const int tid = threadIdx.x;
    const int q   = blockIdx.x >> 3;         // 0..63
    const int t0  = blockIdx.x & 7;
    const int k8l = tid & 15;
    const int rl0 = tid >> 4;
#pragma unroll
    for (int c = 0; c < 4; c++) {
        const int row_local = rl0 + 16 * c;
        const float* src = w + (size_t)(q * 64 + row_local) * DIM + t0 * 128 + k8l * 8;
        float4 v0 = *(const float4*)src;
        float4 v1 = *(const float4*)(src + 4);
        float f[8] = {v0.x, v0.y, v0.z, v0.w, v1.x, v1.y, v1.z, v1.w};
        us8 hv, lv;
#pragma unroll
        for (int e = 0; e < 8; e++) {
            __hip_bfloat16 h = __float2bfloat16(f[e]);
            __hip_bfloat16 l = __float2bfloat16(f[e] - __bfloat162float(h));
            hv[e] = h2u(h); lv[e] = h2u(l);
        }
        const int t    = t0 * 4 + (k8l >> 2);
        const int quad = k8l & 3;
        const size_t frag = ((size_t)q * NT + t) * 256 + c * 64 + quad * 16 + rl0;
        B[frag]                   = hv;   // chunk 0: W_hi
        B[frag + CHUNK_FRAGS]     = hv;   // chunk 1: W_hi
        B[frag + 2 * CHUNK_FRAGS] = lv;   // chunk 2: W_lo
    }
}

// ---------------------------------------------------------------------------
// Barrier-light GEMM. 4 waves per block in 2x2 (wp,wq): block covers 128x128,
// each A/B panel read by 2 waves (second hit served by L1; bare s_barrier per
// K-iter keeps waves lock-stepped). Fragments global->VGPR, reg double-buffer.
// XCD swizzle: each XCD owns 4 qb columns (B L2-resident); consecutive
// per-XCD blocks share pb (A pair fetched once).
__global__ __launch_bounds__(256, 3) void gemm_tanh_kernel(
        const frag_t* __restrict__ A,    // [128][96][4][64] frags
        const frag_t* __restrict__ B,    // [64][96][4][64] frags
        const float* __restrict__ bias,  // [NN]
        float* __restrict__ out) {       // [SEQ][NN]
    const int tid  = threadIdx.x;
    const int lane = tid & 63;
    const int wave = tid >> 6;
    const int wp   = wave >> 1;
    const int wq   = wave & 1;

    const int xcd = blockIdx.x & 7;
    const int idx = blockIdx.x >> 3;         // 0..255 per XCD
    const int pb  = idx >> 2;                // 0..63
    const int qb  = xcd * 4 + (idx & 3);     // 0..31
    const int p   = pb * 2 + wp;             // 0..127
    const int q   = qb * 2 + wq;             // 0..63

    const frag_t* Ab = A + ((size_t)p * NT) * 256 + lane;  // + t*256 + i*64
    const frag_t* Bb = B + ((size_t)q * NT) * 256 + lane;

    f32x4 acc[4][4] = {};
    frag_t a0[4], b0[4], a1[4], b1[4];

#pragma unroll
    for (int i = 0; i < 4; i++) { a0[i] = Ab[i * 64]; b0[i] = Bb[i * 64]; }

    for (int t = 0; t < NT; t += 2) {
        __builtin_amdgcn_s_barrier();        // keep the 4 waves lock-stepped
        const frag_t* An = Ab + (t + 1) * 256;
        const frag_t* Bn = Bb + (t + 1) * 256;
#pragma unroll
        for (int i = 0; i < 4; i++) { a1[i] = An[i * 64]; b1[i] = Bn[i * 64]; }
#pragma unroll
        for (int i = 0; i < 4; i++)
#pragma unroll
            for (int j = 0; j < 4; j++)
                acc[i][j] = __builtin_amdgcn_mfma_f32_16x16x32_bf16(
                    a0[i], b0[j], acc[i][j], 0, 0, 0);

        const int t2 = (t + 2 < NT) ? (t + 2) : 0;   // last prefetch harmless
        const frag_t* An2 = Ab + t2 * 256;
        const frag_t* Bn2 = Bb + t2 * 256;
#pragma unroll
        for (int i = 0; i < 4; i++) { a0[i] = An2[i * 64]; b0[i] = Bn2[i * 64]; }
#pragma unroll
        for (int i = 0; i < 4; i++)
#pragma unroll
            for (int j = 0; j < 4; j++)
                acc[i][j] = __builtin_amdgcn_mfma_f32_16x16x32_bf16(
                    a1[i], b1[j], acc[i][j], 0, 0, 0);
    }

    // Epilogue: C/D layout col = lane&15 (n), row = (lane>>4)*4 + reg (m)
    const int r15  = lane & 15;
    const int quad = lane >> 4;
    const int col0 = q * 64 + r15;
    const int row0 = p * 64 + quad * 4;
#pragma unroll
    for (int j = 0; j < 4; j++) {
        const int col = col0 + j * 16;
        const float bj = bias[col];
#pragma unroll
        for (int i = 0; i < 4; i++) {
            const int row = row0 + i * 16;
#pragma unroll
            for (int r = 0; r < 4; r++)
                out[(size_t)(row + r) * NN + col] = fast_tanh(acc[i][j][r] + bj);
        }
    }
}

// ---------------------------------------------------------------------------
// Fallback (only if workspace too small): naive fp32 tiled GEMM.
__global__ void naive_gemm_kernel(const float* __restrict__ x,
                                  const float* __restrict__ W,
                                  const float* __restrict__ b,
                                  float* __restrict__ out) {
    __shared__ float xs[16][17], ws[16][17];
    int n = blockIdx.x * 16 + threadIdx.x;
    int m = blockIdx.y * 16 + threadIdx.y;
    float s = 0.f;
    for (int k0 = 0; k0 < DIM; k0 += 16) {
        xs[threadIdx.y][threadIdx.x] = x[(size_t)m * DIM + k0 + threadIdx.x];
        ws[threadIdx.y][threadIdx.x] =
            W[(size_t)(blockIdx.x * 16 + threadIdx.y) * DIM + k0 + threadIdx.x];
        __syncthreads();
#pragma unroll
        for (int kk = 0; kk < 16; kk++) s += xs[threadIdx.y][kk] * ws[threadIdx.x][kk];
        __syncthreads();
    }
    out[(size_t)m * NN + n] = tanhf(s + b[n]);
}

// ---------------------------------------------------------------------------
extern "C" void kernel_launch(void* const* d_in, const int* in_sizes, int n_in,
                              void* d_out, int out_size, void* d_ws, size_t ws_size,
                              hipStream_t stream) {
    const float* x = (const float*)d_in[0];
    const float* W = (const float*)d_in[1];
    const float* b = (const float*)d_in[2];
    float* out = (float*)d_out;

    const size_t need = ((size_t)SEQ + (size_t)NN) * KE * sizeof(short);
    if (ws_size < need) {
        dim3 grid(NN / 16, SEQ / 16), block(16, 16);
        naive_gemm_kernel<<<grid, block, 0, stream>>>(x, W, b, out);
        return;
    }

    us8* Abuf = (us8*)d_ws;
    us8* Bbuf = Abuf + (size_t)SEQ * KE / 8;

    convert_x_kernel<<<128 * 8, 256, 0, stream>>>(x, Abuf);   // 1024 blocks
    convert_w_kernel<<<64 * 8, 256, 0, stream>>>(W, Bbuf);    // 512 blocks

    gemm_tanh_kernel<<<2048, 256, 0, stream>>>(
        (const frag_t*)Abuf, (const frag_t*)Bbuf, b, out);
}

// Round 4
// 305.184 us; speedup vs baseline: 1.8432x; 1.3385x over previous
//
#include <hip/hip_runtime.h>
#include <hip/hip_bf16.h>
#include <hip/hip_fp16.h>

#define SEQ 8192
#define DIM 1024
#define NN  4096
// fp16 two-term split: x = x_hi + x_lo (both fp16), W -> W_hi (fp16).
// out = tanh((x_hi + x_lo) . W_hi + b); dropped x.W_lo term ~1e-4 max.
// A layout: [p=0..127][t=0..63][i=0..3][lane][8]  (t<32: x_hi, t>=32: x_lo)
// B layout: [q=0..63][t=0..31][j=0..3][lane][8]   (W_hi only, K=1024)
#define A_FRAGS ((size_t)128 * 64 * 256)
#define B_FRAGS ((size_t)64 * 32 * 256)

using frag_t = __attribute__((ext_vector_type(8))) _Float16;   // 8 f16 = 4 VGPRs
using us8    = __attribute__((ext_vector_type(8))) unsigned short;
using f32x4  = __attribute__((ext_vector_type(4))) float;

__device__ __forceinline__ unsigned short hbits(_Float16 h) {
    unsigned short u; __builtin_memcpy(&u, &h, 2); return u;
}

__device__ __forceinline__ float fast_tanh(float x) {
    float e = __expf(2.0f * x);
    return 1.0f - 2.0f / (e + 1.0f);
}

// ---------------------------------------------------------------------------
// Fused convert. Blocks 0..1023: x -> A (hi+lo). Blocks 1024..1535: W -> B (hi).
// frag = (panel*NT + t)*256 + i*64 + quad*16 + l15 holds
//   elem[row = panel*64 + i*16 + l15][k = t*32 + quad*8 + e].
// Thread map: k8l = tid&15 (t_l = k8l>>2, quad = k8l&3), rl0 = tid>>4 (l15);
// c-loop = i. Reads: 512B contiguous runs; writes: full 64B lines.
__global__ __launch_bounds__(256) void convert_kernel(
        const float* __restrict__ x, const float* __restrict__ w,
        us8* __restrict__ A, us8* __restrict__ B) {
    const int tid  = threadIdx.x;
    const int k8l  = tid & 15;
    const int rl0  = tid >> 4;
    const int t0   = blockIdx.x & 7;
    const int t    = t0 * 4 + (k8l >> 2);
    const int quad = k8l & 3;
    if (blockIdx.x < 1024) {
        const int p = blockIdx.x >> 3;
#pragma unroll
        for (int c = 0; c < 4; c++) {
            const float* src = x + (size_t)(p * 64 + c * 16 + rl0) * DIM + t0 * 128 + k8l * 8;
            float4 v0 = *(const float4*)src;
            float4 v1 = *(const float4*)(src + 4);
            float f[8] = {v0.x, v0.y, v0.z, v0.w, v1.x, v1.y, v1.z, v1.w};
            us8 hv, lv;
#pragma unroll
            for (int e = 0; e < 8; e++) {
                _Float16 h = (_Float16)f[e];
                _Float16 l = (_Float16)(f[e] - (float)h);
                hv[e] = hbits(h); lv[e] = hbits(l);
            }
            const size_t frag = ((size_t)p * 64 + t) * 256 + c * 64 + quad * 16 + rl0;
            A[frag]            = hv;    // tiles 0..31: x_hi
            A[frag + 32 * 256] = lv;    // tiles 32..63: x_lo
        }
    } else {
        const int q = (blockIdx.x - 1024) >> 3;
#pragma unroll
        for (int c = 0; c < 4; c++) {
            const float* src = w + (size_t)(q * 64 + c * 16 + rl0) * DIM + t0 * 128 + k8l * 8;
            float4 v0 = *(const float4*)src;
            float4 v1 = *(const float4*)(src + 4);
            float f[8] = {v0.x, v0.y, v0.z, v0.w, v1.x, v1.y, v1.z, v1.w};
            us8 hv;
#pragma unroll
            for (int e = 0; e < 8; e++) hv[e] = hbits((_Float16)f[e]);
            const size_t frag = ((size_t)q * 32 + t) * 256 + c * 64 + quad * 16 + rl0;
            B[frag] = hv;               // W_hi only
        }
    }
}

// ---------------------------------------------------------------------------
// Barrier-light GEMM, fp16. 4 waves in 2x2 (wp,wq) -> block 128x128; each A/B
// panel read by 2 waves (L1-shared, s_barrier keeps lock-step). Each physical
// B tile register-loaded ONCE and used by both x_hi and x_lo MFMAs (B never
// duplicated: 8.4 MB total, per-XCD slice ~1 MB -> L2-resident). Fragments
// global->VGPR, register double-buffered, no LDS, no full vmcnt drain.
__global__ __launch_bounds__(256, 2) void gemm_tanh_kernel(
        const frag_t* __restrict__ A,    // [128][64][4][64] frags
        const frag_t* __restrict__ B,    // [64][32][4][64] frags
        const float* __restrict__ bias,  // [NN]
        float* __restrict__ out) {       // [SEQ][NN]
    const int tid  = threadIdx.x;
    const int lane = tid & 63;
    const int wave = tid >> 6;
    const int wp   = wave >> 1;
    const int wq   = wave & 1;

    const int xcd = blockIdx.x & 7;
    const int idx = blockIdx.x >> 3;         // 0..255 per XCD
    const int pb  = idx >> 2;                // 0..63
    const int qb  = xcd * 4 + (idx & 3);     // 0..31 (each XCD owns 4 qb)
    const int p   = pb * 2 + wp;             // 0..127
    const int q   = qb * 2 + wq;             // 0..63

    const frag_t* Ab = A + (size_t)p * 64 * 256 + lane;   // + t*256 + i*64
    const frag_t* Bb = B + (size_t)q * 32 * 256 + lane;   // + t*256 + j*64

    f32x4 acc[4][4] = {};
    frag_t ah0[4], al0[4], b0[4], ah1[4], al1[4], b1[4];

#pragma unroll
    for (int i = 0; i < 4; i++) {
        ah0[i] = Ab[i * 64];
        al0[i] = Ab[32 * 256 + i * 64];
        b0[i]  = Bb[i * 64];
    }

    for (int t = 0; t < 32; t += 2) {
        __builtin_amdgcn_s_barrier();        // lock-step for L1 pair-sharing
        const frag_t* An = Ab + (t + 1) * 256;
        const frag_t* Bn = Bb + (t + 1) * 256;
#pragma unroll
        for (int i = 0; i < 4; i++) {
            ah1[i] = An[i * 64];
            al1[i] = An[32 * 256 + i * 64];
            b1[i]  = Bn[i * 64];
        }
#pragma unroll
        for (int i = 0; i < 4; i++)
#pragma unroll
            for (int j = 0; j < 4; j++)
                acc[i][j] = __builtin_amdgcn_mfma_f32_16x16x32_f16(
                    ah0[i], b0[j], acc[i][j], 0, 0, 0);
#pragma unroll
        for (int i = 0; i < 4; i++)
#pragma unroll
            for (int j = 0; j < 4; j++)
                acc[i][j] = __builtin_amdgcn_mfma_f32_16x16x32_f16(
                    al0[i], b0[j], acc[i][j], 0, 0, 0);

        const int t2 = (t + 2 < 32) ? (t + 2) : 0;   // last prefetch harmless
        const frag_t* An2 = Ab + t2 * 256;
        const frag_t* Bn2 = Bb + t2 * 256;
#pragma unroll
        for (int i = 0; i < 4; i++) {
            ah0[i] = An2[i * 64];
            al0[i] = An2[32 * 256 + i * 64];
            b0[i]  = Bn2[i * 64];
        }
#pragma unroll
        for (int i = 0; i < 4; i++)
#pragma unroll
            for (int j = 0; j < 4; j++)
                acc[i][j] = __builtin_amdgcn_mfma_f32_16x16x32_f16(
                    ah1[i], b1[j], acc[i][j], 0, 0, 0);
#pragma unroll
        for (int i = 0; i < 4; i++)
#pragma unroll
            for (int j = 0; j < 4; j++)
                acc[i][j] = __builtin_amdgcn_mfma_f32_16x16x32_f16(
                    al1[i], b1[j], acc[i][j], 0, 0, 0);
    }

    // Epilogue: C/D layout col = lane&15 (n), row = (lane>>4)*4 + reg (m)
    const int r15  = lane & 15;
    const int quad = lane >> 4;
    const int col0 = q * 64 + r15;
    const int row0 = p * 64 + quad * 4;
#pragma unroll
    for (int j = 0; j < 4; j++) {
        const int col = col0 + j * 16;
        const float bj = bias[col];
#pragma unroll
        for (int i = 0; i < 4; i++) {
            const int row = row0 + i * 16;
#pragma unroll
            for (int r = 0; r < 4; r++)
                out[(size_t)(row + r) * NN + col] = fast_tanh(acc[i][j][r] + bj);
        }
    }
}

// ---------------------------------------------------------------------------
// Fallback (only if workspace too small): naive fp32 tiled GEMM.
__global__ void naive_gemm_kernel(const float* __restrict__ x,
                                  const float* __restrict__ W,
                                  const float* __restrict__ b,
                                  float* __restrict__ out) {
    __shared__ float xs[16][17], ws[16][17];
    int n = blockIdx.x * 16 + threadIdx.x;
    int m = blockIdx.y * 16 + threadIdx.y;
    float s = 0.f;
    for (int k0 = 0; k0 < DIM; k0 += 16) {
        xs[threadIdx.y][threadIdx.x] = x[(size_t)m * DIM + k0 + threadIdx.x];
        ws[threadIdx.y][threadIdx.x] =
            W[(size_t)(blockIdx.x * 16 + threadIdx.y) * DIM + k0 + threadIdx.x];
        __syncthreads();
#pragma unroll
        for (int kk = 0; kk < 16; kk++) s += xs[threadIdx.y][kk] * ws[threadIdx.x][kk];
        __syncthreads();
    }
    out[(size_t)m * NN + n] = tanhf(s + b[n]);
}

// ---------------------------------------------------------------------------
extern "C" void kernel_launch(void* const* d_in, const int* in_sizes, int n_in,
                              void* d_out, int out_size, void* d_ws, size_t ws_size,
                              hipStream_t stream) {
    const float* x = (const float*)d_in[0];
    const float* W = (const float*)d_in[1];
    const float* b = (const float*)d_in[2];
    float* out = (float*)d_out;

    const size_t need = (A_FRAGS + B_FRAGS) * 16;   // ~42 MB
    if (ws_size < need) {
        dim3 grid(NN / 16, SEQ / 16), block(16, 16);
        naive_gemm_kernel<<<grid, block, 0, stream>>>(x, W, b, out);
        return;
    }

    us8* Abuf = (us8*)d_ws;
    us8* Bbuf = Abuf + A_FRAGS;

    convert_kernel<<<1536, 256, 0, stream>>>(x, W, Abuf, Bbuf);

    gemm_tanh_kernel<<<2048, 256, 0, stream>>>(
        (const frag_t*)Abuf, (const frag_t*)Bbuf, b, out);
}